// Round 1
// baseline (1015.754 us; speedup 1.0000x reference)
//
#include <hip/hip_runtime.h>
#include <math.h>

#define IN_DIM    1024
#define CTX_DIM   768
#define NUM_HEADS 16
#define HEAD_DIM  64
#define BATCH     8
#define NQ        1024
#define NKV       512
#define SCALE     0.125f   // 1/sqrt(64)

// ---------------------------------------------------------------------------
// Generic GEMM: C[M,N] = A[M,K] @ W[N,K]^T + bias[N]
// Both A and W are row-major with contiguous K -> "NT" dot-product GEMM.
// 128x128 tile, BK=32, 256 threads, 8x8 outputs/thread.
// LDS stored k-major ([BK][128+4]) so fragment reads are float4.
// ---------------------------------------------------------------------------
__global__ __launch_bounds__(256)
void gemm_nt_bias(const float* __restrict__ A, const float* __restrict__ W,
                  const float* __restrict__ bias, float* __restrict__ C,
                  int M, int N, int K)
{
    constexpr int BM = 128, BN = 128, BK = 32;
    __shared__ float As[BK][BM + 4];
    __shared__ float Ws[BK][BN + 4];

    const int tid = threadIdx.x;
    const int tx  = tid & 15;          // n-group (8 cols each)
    const int ty  = tid >> 4;          // m-group (8 rows each)
    const int m0  = blockIdx.y * BM;
    const int n0  = blockIdx.x * BN;

    float acc[8][8] = {};

    const int nk = K / BK;             // K is 768 or 1024: divisible by 32
    for (int kt = 0; kt < nk; ++kt) {
        const int k0 = kt * BK;
        // Stage A tile: 128 rows x 32 k = 1024 float4; 4 per thread.
        #pragma unroll
        for (int t = 0; t < 4; ++t) {
            int i  = tid + t * 256;
            int r  = i >> 3;            // 8 float4 per row
            int c4 = i & 7;
            float4 v = *(const float4*)(A + (size_t)(m0 + r) * K + k0 + c4 * 4);
            As[c4*4+0][r] = v.x; As[c4*4+1][r] = v.y;
            As[c4*4+2][r] = v.z; As[c4*4+3][r] = v.w;
        }
        // Stage W tile.
        #pragma unroll
        for (int t = 0; t < 4; ++t) {
            int i  = tid + t * 256;
            int r  = i >> 3;
            int c4 = i & 7;
            float4 v = *(const float4*)(W + (size_t)(n0 + r) * K + k0 + c4 * 4);
            Ws[c4*4+0][r] = v.x; Ws[c4*4+1][r] = v.y;
            Ws[c4*4+2][r] = v.z; Ws[c4*4+3][r] = v.w;
        }
        __syncthreads();

        #pragma unroll
        for (int k = 0; k < BK; ++k) {
            float4 a0 = *(const float4*)&As[k][ty*8];
            float4 a1 = *(const float4*)&As[k][ty*8+4];
            float4 w0 = *(const float4*)&Ws[k][tx*8];
            float4 w1 = *(const float4*)&Ws[k][tx*8+4];
            float av[8] = {a0.x,a0.y,a0.z,a0.w,a1.x,a1.y,a1.z,a1.w};
            float wv[8] = {w0.x,w0.y,w0.z,w0.w,w1.x,w1.y,w1.z,w1.w};
            #pragma unroll
            for (int i = 0; i < 8; ++i)
                #pragma unroll
                for (int j = 0; j < 8; ++j)
                    acc[i][j] = fmaf(av[i], wv[j], acc[i][j]);
        }
        __syncthreads();
    }

    // Epilogue: bias + float4 stores.
    #pragma unroll
    for (int i = 0; i < 8; ++i) {
        int m = m0 + ty*8 + i;
        float* crow = C + (size_t)m * N + n0 + tx*8;
        const float* brow = bias + n0 + tx*8;
        float4 c0, c1;
        c0.x = acc[i][0] + brow[0]; c0.y = acc[i][1] + brow[1];
        c0.z = acc[i][2] + brow[2]; c0.w = acc[i][3] + brow[3];
        c1.x = acc[i][4] + brow[4]; c1.y = acc[i][5] + brow[5];
        c1.z = acc[i][6] + brow[6]; c1.w = acc[i][7] + brow[7];
        *(float4*)crow       = c0;
        *(float4*)(crow + 4) = c1;
    }
}

// ---------------------------------------------------------------------------
// Flash-style attention over one (b, h, q-tile of 64).
// Q/K/V buffers are [B*N, IN_DIM] with head h at columns h*64..h*64+63.
// 256 threads: 16x16 grid, 4x4 outputs per thread in both GEMMs
// (ty -> q rows, tx -> kv cols in S-GEMM / d cols in PV-GEMM).
// Online softmax with per-row (m, l) replicated across the 16-lane row group.
// ---------------------------------------------------------------------------
__global__ __launch_bounds__(256)
void attn_kernel(const float* __restrict__ Q, const float* __restrict__ Kb,
                 const float* __restrict__ Vb, float* __restrict__ O)
{
    __shared__ float Qs[64][68];
    __shared__ float Ks[64][68];   // stored with per-row column rotation (row>>2)
    __shared__ float Vs[64][68];
    __shared__ float Ps[64][68];

    const int qt  = blockIdx.x;    // 0..15
    const int h   = blockIdx.y;    // 0..15
    const int b   = blockIdx.z;    // 0..7
    const int tid = threadIdx.x;
    const int tx  = tid & 15;
    const int ty  = tid >> 4;

    const int q0 = qt * 64;
    const float* qptr = Q + ((size_t)(b * NQ + q0)) * IN_DIM + h * HEAD_DIM;

    // Load Q tile (64 x 64): 1024 float4, 4 per thread.
    for (int i = tid; i < 64 * 16; i += 256) {
        int r = i >> 4, c4 = i & 15;
        *(float4*)&Qs[r][c4 * 4] =
            *(const float4*)(qptr + (size_t)r * IN_DIM + c4 * 4);
    }

    float m_run[4], l_run[4];
    float o_acc[4][4] = {};
    #pragma unroll
    for (int i = 0; i < 4; ++i) { m_run[i] = -1e30f; l_run[i] = 0.0f; }

    for (int kt = 0; kt < NKV / 64; ++kt) {
        const int kv0 = kt * 64;
        const float* kptr = Kb + ((size_t)(b * NKV + kv0)) * IN_DIM + h * HEAD_DIM;
        const float* vptr = Vb + ((size_t)(b * NKV + kv0)) * IN_DIM + h * HEAD_DIM;

        __syncthreads();   // previous PV done -> safe to overwrite Ks/Vs
        for (int i = tid; i < 64 * 16; i += 256) {
            int r = i >> 4, c4 = i & 15;
            float4 kv4 = *(const float4*)(kptr + (size_t)r * IN_DIM + c4 * 4);
            int pc4 = (c4 + (r >> 2)) & 15;              // bank-rotation
            *(float4*)&Ks[r][pc4 * 4] = kv4;
            *(float4*)&Vs[r][c4 * 4] =
                *(const float4*)(vptr + (size_t)r * IN_DIM + c4 * 4);
        }
        __syncthreads();

        // ---- S = Q K^T * SCALE  (thread: q rows ty*4+i, kv cols tx*4+j) ----
        float s[4][4] = {};
        #pragma unroll
        for (int d4 = 0; d4 < 16; ++d4) {
            float qv[4][4], kv[4][4];
            #pragma unroll
            for (int i = 0; i < 4; ++i) {
                float4 t = *(const float4*)&Qs[ty*4 + i][d4 * 4];
                qv[i][0]=t.x; qv[i][1]=t.y; qv[i][2]=t.z; qv[i][3]=t.w;
            }
            #pragma unroll
            for (int j = 0; j < 4; ++j) {
                int row = tx*4 + j;
                int pc4 = (d4 + (row >> 2)) & 15;        // undo rotation
                float4 t = *(const float4*)&Ks[row][pc4 * 4];
                kv[j][0]=t.x; kv[j][1]=t.y; kv[j][2]=t.z; kv[j][3]=t.w;
            }
            #pragma unroll
            for (int i = 0; i < 4; ++i)
                #pragma unroll
                for (int j = 0; j < 4; ++j)
                    #pragma unroll
                    for (int u = 0; u < 4; ++u)
                        s[i][j] = fmaf(qv[i][u], kv[j][u], s[i][j]);
        }

        // ---- online softmax (row groups = 16 consecutive lanes) ----
        float corr[4];
        #pragma unroll
        for (int i = 0; i < 4; ++i) {
            float rmax = -1e30f;
            #pragma unroll
            for (int j = 0; j < 4; ++j) {
                s[i][j] *= SCALE;
                rmax = fmaxf(rmax, s[i][j]);
            }
            #pragma unroll
            for (int off = 1; off < 16; off <<= 1)
                rmax = fmaxf(rmax, __shfl_xor(rmax, off));
            float m_new = fmaxf(m_run[i], rmax);
            corr[i] = __expf(m_run[i] - m_new);
            float rsum = 0.0f;
            #pragma unroll
            for (int j = 0; j < 4; ++j) {
                s[i][j] = __expf(s[i][j] - m_new);
                rsum += s[i][j];
            }
            #pragma unroll
            for (int off = 1; off < 16; off <<= 1)
                rsum += __shfl_xor(rsum, off);
            l_run[i] = l_run[i] * corr[i] + rsum;
            m_run[i] = m_new;
            // write P row fragment
            *(float4*)&Ps[ty*4 + i][tx*4] = make_float4(s[i][0], s[i][1], s[i][2], s[i][3]);
        }
        __syncthreads();

        // ---- O = O*corr + P V  (thread: q rows ty*4+i, d cols tx*4+j) ----
        #pragma unroll
        for (int i = 0; i < 4; ++i)
            #pragma unroll
            for (int j = 0; j < 4; ++j)
                o_acc[i][j] *= corr[i];

        #pragma unroll
        for (int kv4 = 0; kv4 < 16; ++kv4) {
            float pv[4][4], vv[4][4];
            #pragma unroll
            for (int i = 0; i < 4; ++i) {
                float4 t = *(const float4*)&Ps[ty*4 + i][kv4 * 4];
                pv[i][0]=t.x; pv[i][1]=t.y; pv[i][2]=t.z; pv[i][3]=t.w;
            }
            #pragma unroll
            for (int u = 0; u < 4; ++u) {
                float4 t = *(const float4*)&Vs[kv4*4 + u][tx * 4];
                vv[u][0]=t.x; vv[u][1]=t.y; vv[u][2]=t.z; vv[u][3]=t.w;
            }
            #pragma unroll
            for (int i = 0; i < 4; ++i)
                #pragma unroll
                for (int u = 0; u < 4; ++u)
                    #pragma unroll
                    for (int j = 0; j < 4; ++j)
                        o_acc[i][j] = fmaf(pv[i][u], vv[u][j], o_acc[i][j]);
        }
    }

    // ---- finalize: divide by l, store ----
    #pragma unroll
    for (int i = 0; i < 4; ++i) {
        float inv = 1.0f / l_run[i];
        float4 o;
        o.x = o_acc[i][0] * inv; o.y = o_acc[i][1] * inv;
        o.z = o_acc[i][2] * inv; o.w = o_acc[i][3] * inv;
        *(float4*)(O + ((size_t)(b * NQ + q0 + ty*4 + i)) * IN_DIM
                     + h * HEAD_DIM + tx * 4) = o;
    }
}

// ---------------------------------------------------------------------------
extern "C" void kernel_launch(void* const* d_in, const int* in_sizes, int n_in,
                              void* d_out, int out_size, void* d_ws, size_t ws_size,
                              hipStream_t stream)
{
    const float* x   = (const float*)d_in[0];   // [8,1024,1024]
    const float* ctx = (const float*)d_in[1];   // [8,512,768]
    const float* Wq  = (const float*)d_in[2];   // [1024,1024]
    const float* bq  = (const float*)d_in[3];
    const float* Wk  = (const float*)d_in[4];   // [1024,768]
    const float* bk  = (const float*)d_in[5];
    const float* Wv  = (const float*)d_in[6];   // [1024,768]
    const float* bv  = (const float*)d_in[7];
    const float* Wo  = (const float*)d_in[8];   // [1024,1024]
    const float* bo  = (const float*)d_in[9];
    float* out = (float*)d_out;

    // Workspace layout (floats): Q[8192*1024] K[4096*1024] V[4096*1024] A[8192*1024]
    float* Qb = (float*)d_ws;
    float* Kb = Qb + (size_t)BATCH * NQ  * IN_DIM;   // +8388608
    float* Vb = Kb + (size_t)BATCH * NKV * IN_DIM;   // +4194304
    float* Ab = Vb + (size_t)BATCH * NKV * IN_DIM;   // +4194304
    // total 96 MB

    const int MQ = BATCH * NQ;    // 8192
    const int MK = BATCH * NKV;   // 4096

    // Projections
    gemm_nt_bias<<<dim3(IN_DIM/128, MQ/128), 256, 0, stream>>>(x,   Wq, bq, Qb, MQ, IN_DIM, IN_DIM);
    gemm_nt_bias<<<dim3(IN_DIM/128, MK/128), 256, 0, stream>>>(ctx, Wk, bk, Kb, MK, IN_DIM, CTX_DIM);
    gemm_nt_bias<<<dim3(IN_DIM/128, MK/128), 256, 0, stream>>>(ctx, Wv, bv, Vb, MK, IN_DIM, CTX_DIM);

    // Attention: grid (q-tiles, heads, batch)
    attn_kernel<<<dim3(NQ/64, NUM_HEADS, BATCH), 256, 0, stream>>>(Qb, Kb, Vb, Ab);

    // Output projection
    gemm_nt_bias<<<dim3(IN_DIM/128, MQ/128), 256, 0, stream>>>(Ab, Wo, bo, out, MQ, IN_DIM, IN_DIM);
}

// Round 2
// 258.919 us; speedup vs baseline: 3.9231x; 3.9231x over previous
//
#include <hip/hip_runtime.h>
#include <math.h>

#define IN_DIM    1024
#define CTX_DIM   768
#define NUM_HEADS 16
#define HEAD_DIM  64
#define BATCH     8
#define NQ        1024
#define NKV       512
#define SCALE     0.125f   // 1/sqrt(64)

typedef __attribute__((ext_vector_type(8))) _Float16 f16x8;
typedef __attribute__((ext_vector_type(4))) _Float16 f16x4;
typedef __attribute__((ext_vector_type(4))) float    f32x4;

// async global->LDS, 16B per lane. lds dest must be wave-uniform base
// (HW adds lane*16). src is per-lane.
__device__ __forceinline__ void async16(const void* g, void* l) {
    __builtin_amdgcn_global_load_lds(
        (const __attribute__((address_space(1))) void*)g,
        (__attribute__((address_space(3))) void*)l, 16, 0, 0);
}

// ---------------------------------------------------------------------------
// fp32 -> fp16 conversion of x, context, Wq, Wk, Wv, Wo into one contiguous
// fp16 region (segment offsets hardcoded, float4 granularity).
// ---------------------------------------------------------------------------
__global__ __launch_bounds__(256)
void cvt6(const float* __restrict__ s0, const float* __restrict__ s1,
          const float* __restrict__ s2, const float* __restrict__ s3,
          const float* __restrict__ s4, const float* __restrict__ s5,
          _Float16* __restrict__ dst)
{
    const int stride = gridDim.x * blockDim.x;
    for (int i = blockIdx.x * blockDim.x + threadIdx.x; i < 3801088; i += stride) {
        const float* s; int loc;
        if      (i < 2097152) { s = s0; loc = i; }
        else if (i < 2883584) { s = s1; loc = i - 2097152; }
        else if (i < 3145728) { s = s2; loc = i - 2883584; }
        else if (i < 3342336) { s = s3; loc = i - 3145728; }
        else if (i < 3538944) { s = s4; loc = i - 3342336; }
        else                  { s = s5; loc = i - 3538944; }
        float4 v = *(const float4*)(s + (size_t)loc * 4);
        f16x4 o;
        o.x = (_Float16)v.x; o.y = (_Float16)v.y;
        o.z = (_Float16)v.z; o.w = (_Float16)v.w;
        *(f16x4*)(dst + (size_t)i * 4) = o;
    }
}

// ---------------------------------------------------------------------------
// MFMA GEMM: C[M,N] = A[M,K](fp16) @ W[N,K](fp16)^T + bias(fp32)
// BM=128, BK=64, BN template (128 or 64). 256 threads = 4 waves (2x2).
// LDS row = 64 fp16 = 128B = 8 slots of 16B; slot s holds logical slot
// s ^ (row&7)  (pre-swizzled global source + deswizzled read -> conflict-free
// ds_read_b128). Staged with global_load_lds dwordx4.
// ---------------------------------------------------------------------------
template<int BN, typename OutT>
__global__ __launch_bounds__(256)
void gemm_h(const _Float16* __restrict__ A, const _Float16* __restrict__ W,
            const float* __restrict__ bias, OutT* __restrict__ C,
            int M, int N, int K)
{
    constexpr int BM = 128, BK = 64;
    constexpr int NF = BN / 32;               // n-frags per wave
    __shared__ alignas(16) _Float16 As[BM * BK];
    __shared__ alignas(16) _Float16 Ws[BN * BK];

    const int tid = threadIdx.x;
    const int l   = tid & 63;
    const int w   = tid >> 6;
    const int wr  = w >> 1, wc = w & 1;
    const int m0  = blockIdx.y * BM;
    const int n0  = blockIdx.x * BN;

    f32x4 acc[4][NF];
    #pragma unroll
    for (int m = 0; m < 4; ++m)
        #pragma unroll
        for (int n = 0; n < NF; ++n)
            acc[m][n] = (f32x4){0.f, 0.f, 0.f, 0.f};

    const int nk = K / BK;
    for (int kt = 0; kt < nk; ++kt) {
        const int k0 = kt * BK;
        #pragma unroll
        for (int it = 0; it < 4; ++it) {          // A: 128 rows x 8 slots
            int e = it * 256 + tid;
            int r = e >> 3, p = e & 7;
            async16(A + (size_t)(m0 + r) * K + k0 + ((p ^ (r & 7)) * 8),
                    &As[(size_t)(it * 256 + (tid & ~63)) * 8]);
        }
        #pragma unroll
        for (int it = 0; it < BN / 32; ++it) {    // W: BN rows x 8 slots
            int e = it * 256 + tid;
            int r = e >> 3, p = e & 7;
            async16(W + (size_t)(n0 + r) * K + k0 + ((p ^ (r & 7)) * 8),
                    &Ws[(size_t)(it * 256 + (tid & ~63)) * 8]);
        }
        __syncthreads();   // drains vmcnt -> tiles visible

        #pragma unroll
        for (int kk = 0; kk < 2; ++kk) {
            f16x8 af[4], bf[NF];
            #pragma unroll
            for (int m = 0; m < 4; ++m) {
                int rr = wr * 64 + m * 16 + (l & 15);
                int slot = (kk * 4 + (l >> 4)) ^ (rr & 7);
                af[m] = *(const f16x8*)&As[rr * 64 + slot * 8];
            }
            #pragma unroll
            for (int n = 0; n < NF; ++n) {
                int rr = wc * (BN / 2) + n * 16 + (l & 15);
                int slot = (kk * 4 + (l >> 4)) ^ (rr & 7);
                bf[n] = *(const f16x8*)&Ws[rr * 64 + slot * 8];
            }
            #pragma unroll
            for (int m = 0; m < 4; ++m)
                #pragma unroll
                for (int n = 0; n < NF; ++n)
                    acc[m][n] = __builtin_amdgcn_mfma_f32_16x16x32_f16(
                        af[m], bf[n], acc[m][n], 0, 0, 0);
        }
        __syncthreads();   // compute done -> safe to restage
    }

    // epilogue: C/D layout col = l&15, row = (l>>4)*4 + reg
    float bv[NF];
    #pragma unroll
    for (int n = 0; n < NF; ++n)
        bv[n] = bias[n0 + wc * (BN / 2) + n * 16 + (l & 15)];
    #pragma unroll
    for (int m = 0; m < 4; ++m)
        #pragma unroll
        for (int n = 0; n < NF; ++n)
            #pragma unroll
            for (int r = 0; r < 4; ++r) {
                int row = m0 + wr * 64 + m * 16 + (l >> 4) * 4 + r;
                int col = n0 + wc * (BN / 2) + n * 16 + (l & 15);
                C[(size_t)row * N + col] = (OutT)(acc[m][n][r] + bv[n]);
            }
}

// ---------------------------------------------------------------------------
// V transpose: Vh[b*NKV+kv][h*64+d] -> Vt[((b*16+h)*64+d)*512 + kv]
// so attention can stage V as a [n=d][k=kv] B-operand with global_load_lds.
// ---------------------------------------------------------------------------
__global__ __launch_bounds__(256)
void transpose_v(const _Float16* __restrict__ Vh, _Float16* __restrict__ Vt)
{
    __shared__ alignas(16) _Float16 Ts[64 * 72];   // [kv][d], stride 72 hw
    const int tid = threadIdx.x;
    const int kvt = blockIdx.x, h = blockIdx.y, b = blockIdx.z;
    const int kv0 = kvt * 64;
    #pragma unroll
    for (int it = 0; it < 2; ++it) {
        int g = it * 256 + tid;
        int kv = g >> 3, d0 = (g & 7) * 8;
        *(f16x8*)&Ts[kv * 72 + d0] =
            *(const f16x8*)(Vh + (size_t)(b * NKV + kv0 + kv) * IN_DIM + h * 64 + d0);
    }
    __syncthreads();
    #pragma unroll
    for (int it = 0; it < 2; ++it) {
        int g = it * 256 + tid;
        int d = g >> 3, k0 = (g & 7) * 8;
        f16x8 v;
        #pragma unroll
        for (int j = 0; j < 8; ++j) v[j] = Ts[(k0 + j) * 72 + d];
        *(f16x8*)(Vt + ((size_t)((b * 16 + h) * 64 + d)) * NKV + kv0 + k0) = v;
    }
}

// ---------------------------------------------------------------------------
// MFMA flash attention. Block = (qtile 64, h, b), 4 waves x 16 q-rows.
// Q in regs (2 A-frags), K & Vt staged in LDS (swizzled, 64x128B),
// online softmax in f32, P -> per-wave LDS (stride 176B) -> PV A-frags.
// ---------------------------------------------------------------------------
__global__ __launch_bounds__(256)
void attn_mfma(const _Float16* __restrict__ Qh, const _Float16* __restrict__ Kh,
               const _Float16* __restrict__ Vt, _Float16* __restrict__ Ah)
{
    __shared__ alignas(16) _Float16 Ks[64 * 64];   // [kv][d] swizzled
    __shared__ alignas(16) _Float16 Vs[64 * 64];   // [d][kv] swizzled
    __shared__ alignas(16) _Float16 Pl[4][16 * 88];// per-wave P, stride 88 hw

    const int tid = threadIdx.x;
    const int l = tid & 63, w = tid >> 6;
    const int qt = blockIdx.x, h = blockIdx.y, b = blockIdx.z;
    const int q0 = qt * 64;

    // Q A-frags: lane l -> q-row w*16 + (l&15), k = kk*32 + (l>>4)*8 + j
    f16x8 qa[2];
    {
        const _Float16* qp = Qh + (size_t)(b * NQ + q0 + w * 16 + (l & 15)) * IN_DIM
                                + h * 64 + (l >> 4) * 8;
        qa[0] = *(const f16x8*)qp;
        qa[1] = *(const f16x8*)(qp + 32);
    }

    float m_run[4], l_run[4];
    f32x4 of[4];
    #pragma unroll
    for (int r = 0; r < 4; ++r) { m_run[r] = -1e30f; l_run[r] = 0.f; }
    #pragma unroll
    for (int d = 0; d < 4; ++d) of[d] = (f32x4){0.f, 0.f, 0.f, 0.f};

    for (int kt = 0; kt < NKV / 64; ++kt) {
        const int kv0 = kt * 64;
        __syncthreads();   // prev PV done -> safe to restage
        #pragma unroll
        for (int it = 0; it < 2; ++it) {           // K tile: 64 rows x 8 slots
            int e = it * 256 + tid;
            int r = e >> 3, p = e & 7;
            async16(Kh + (size_t)(b * NKV + kv0 + r) * IN_DIM + h * 64 + ((p ^ (r & 7)) * 8),
                    &Ks[(size_t)(it * 256 + (tid & ~63)) * 8]);
        }
        #pragma unroll
        for (int it = 0; it < 2; ++it) {           // Vt tile: 64 d-rows x 8 slots
            int e = it * 256 + tid;
            int r = e >> 3, p = e & 7;
            async16(Vt + ((size_t)((b * 16 + h) * 64 + r)) * NKV + kv0 + ((p ^ (r & 7)) * 8),
                    &Vs[(size_t)(it * 256 + (tid & ~63)) * 8]);
        }
        __syncthreads();

        // ---- S = Q K^T ----
        f32x4 sf[4];
        #pragma unroll
        for (int n = 0; n < 4; ++n) sf[n] = (f32x4){0.f, 0.f, 0.f, 0.f};
        #pragma unroll
        for (int kk = 0; kk < 2; ++kk)
            #pragma unroll
            for (int n = 0; n < 4; ++n) {
                int rr = n * 16 + (l & 15);
                int slot = (kk * 4 + (l >> 4)) ^ (rr & 7);
                f16x8 kb = *(const f16x8*)&Ks[rr * 64 + slot * 8];
                sf[n] = __builtin_amdgcn_mfma_f32_16x16x32_f16(qa[kk], kb, sf[n], 0, 0, 0);
            }

        // ---- online softmax: row q = (l>>4)*4 + r, col kv = n*16 + (l&15) ----
        float corr[4];
        #pragma unroll
        for (int r = 0; r < 4; ++r) {
            float mx = -1e30f;
            #pragma unroll
            for (int n = 0; n < 4; ++n) mx = fmaxf(mx, sf[n][r] * SCALE);
            #pragma unroll
            for (int off = 1; off < 16; off <<= 1) mx = fmaxf(mx, __shfl_xor(mx, off));
            float mnew = fmaxf(m_run[r], mx);
            corr[r] = __expf(m_run[r] - mnew);
            float rs = 0.f;
            #pragma unroll
            for (int n = 0; n < 4; ++n) {
                float p = __expf(sf[n][r] * SCALE - mnew);
                sf[n][r] = p;
                rs += p;
            }
            #pragma unroll
            for (int off = 1; off < 16; off <<= 1) rs += __shfl_xor(rs, off);
            l_run[r] = l_run[r] * corr[r] + rs;
            m_run[r] = mnew;
        }

        // write P (fp16) to per-wave LDS
        #pragma unroll
        for (int n = 0; n < 4; ++n)
            #pragma unroll
            for (int r = 0; r < 4; ++r)
                Pl[w][((l >> 4) * 4 + r) * 88 + n * 16 + (l & 15)] = (_Float16)sf[n][r];

        // rescale O
        #pragma unroll
        for (int d = 0; d < 4; ++d)
            #pragma unroll
            for (int r = 0; r < 4; ++r) of[d][r] *= corr[r];

        // ---- PV: A = P[16q x 64kv] from Pl, B = Vt frags ----
        #pragma unroll
        for (int kk = 0; kk < 2; ++kk) {
            f16x8 pa = *(const f16x8*)&Pl[w][(l & 15) * 88 + kk * 32 + (l >> 4) * 8];
            #pragma unroll
            for (int d = 0; d < 4; ++d) {
                int rr = d * 16 + (l & 15);
                int slot = (kk * 4 + (l >> 4)) ^ (rr & 7);
                f16x8 vb = *(const f16x8*)&Vs[rr * 64 + slot * 8];
                of[d] = __builtin_amdgcn_mfma_f32_16x16x32_f16(pa, vb, of[d], 0, 0, 0);
            }
        }
    }

    // ---- finalize ----
    float inv[4];
    #pragma unroll
    for (int r = 0; r < 4; ++r) inv[r] = 1.f / l_run[r];
    #pragma unroll
    for (int d = 0; d < 4; ++d)
        #pragma unroll
        for (int r = 0; r < 4; ++r) {
            size_t row = (size_t)(b * NQ + q0 + w * 16 + (l >> 4) * 4 + r);
            Ah[row * IN_DIM + h * 64 + d * 16 + (l & 15)] = (_Float16)(of[d][r] * inv[r]);
        }
}

// ---------------------------------------------------------------------------
extern "C" void kernel_launch(void* const* d_in, const int* in_sizes, int n_in,
                              void* d_out, int out_size, void* d_ws, size_t ws_size,
                              hipStream_t stream)
{
    const float* x   = (const float*)d_in[0];
    const float* ctx = (const float*)d_in[1];
    const float* Wq  = (const float*)d_in[2];
    const float* bq  = (const float*)d_in[3];
    const float* Wk  = (const float*)d_in[4];
    const float* bk  = (const float*)d_in[5];
    const float* Wv  = (const float*)d_in[6];
    const float* bv  = (const float*)d_in[7];
    const float* Wo  = (const float*)d_in[8];
    const float* bo  = (const float*)d_in[9];
    float* out = (float*)d_out;

    // fp16 workspace layout (halfword offsets)
    _Float16* H = (_Float16*)d_ws;
    _Float16* xh   = H +        0;  // 8388608
    _Float16* ctxh = H +  8388608;  // 3145728
    _Float16* wqh  = H + 11534336;  // 1048576
    _Float16* wkh  = H + 12582912;  //  786432
    _Float16* wvh  = H + 13369344;  //  786432
    _Float16* woh  = H + 14155776;  // 1048576
    _Float16* Qh   = H + 15204352;  // 8388608
    _Float16* Kh   = H + 23592960;  // 4194304
    _Float16* Vh   = H + 27787264;  // 4194304
    _Float16* Vth  = H + 31981568;  // 4194304
    _Float16* Ah   = H + 36175872;  // 8388608  (end 44564480 hw = 89.1 MB)

    const int MQ = BATCH * NQ;    // 8192
    const int MK = BATCH * NKV;   // 4096

    // 1) convert all fp32 inputs to fp16
    cvt6<<<2048, 256, 0, stream>>>(x, ctx, Wq, Wk, Wv, Wo, xh);

    // 2) projections (fp16 out)
    gemm_h<128, _Float16><<<dim3(IN_DIM/128, MQ/128), 256, 0, stream>>>(
        xh, wqh, bq, Qh, MQ, IN_DIM, IN_DIM);
    gemm_h<64, _Float16><<<dim3(IN_DIM/64, MK/128), 256, 0, stream>>>(
        ctxh, wkh, bk, Kh, MK, IN_DIM, CTX_DIM);
    gemm_h<64, _Float16><<<dim3(IN_DIM/64, MK/128), 256, 0, stream>>>(
        ctxh, wvh, bv, Vh, MK, IN_DIM, CTX_DIM);

    // 3) V -> [b,h,d,kv]
    transpose_v<<<dim3(NKV/64, NUM_HEADS, BATCH), 256, 0, stream>>>(Vh, Vth);

    // 4) attention
    attn_mfma<<<dim3(NQ/64, NUM_HEADS, BATCH), 256, 0, stream>>>(Qh, Kh, Vth, Ah);

    // 5) output projection (fp32 out)
    gemm_h<128, float><<<dim3(IN_DIM/128, MQ/128), 256, 0, stream>>>(
        Ah, woh, bo, out, MQ, IN_DIM, IN_DIM);
}

// Round 3
// 252.693 us; speedup vs baseline: 4.0197x; 1.0246x over previous
//
#include <hip/hip_runtime.h>
#include <math.h>

#define IN_DIM    1024
#define CTX_DIM   768
#define NUM_HEADS 16
#define HEAD_DIM  64
#define BATCH     8
#define NQ        1024
#define NKV       512
#define SCALE     0.125f   // 1/sqrt(64)

typedef __attribute__((ext_vector_type(8))) _Float16 f16x8;
typedef __attribute__((ext_vector_type(4))) _Float16 f16x4;
typedef __attribute__((ext_vector_type(4))) float    f32x4;

// async global->LDS, 16B per lane. lds dest must be wave-uniform base
// (HW adds lane*16). src is per-lane.
__device__ __forceinline__ void async16(const void* g, void* l) {
    __builtin_amdgcn_global_load_lds(
        (const __attribute__((address_space(1))) void*)g,
        (__attribute__((address_space(3))) void*)l, 16, 0, 0);
}

// native 2^x
__device__ __forceinline__ float fexp2(float x) {
    float r; asm("v_exp_f32 %0, %1" : "=v"(r) : "v"(x)); return r;
}

// ---------------------------------------------------------------------------
// fp32 -> fp16 conversion of x, context, Wq, Wk, Wv, Wo into one contiguous
// fp16 region (segment offsets hardcoded, float4 granularity).
// ---------------------------------------------------------------------------
__global__ __launch_bounds__(256)
void cvt6(const float* __restrict__ s0, const float* __restrict__ s1,
          const float* __restrict__ s2, const float* __restrict__ s3,
          const float* __restrict__ s4, const float* __restrict__ s5,
          _Float16* __restrict__ dst)
{
    const int stride = gridDim.x * blockDim.x;
    for (int i = blockIdx.x * blockDim.x + threadIdx.x; i < 3801088; i += stride) {
        const float* s; int loc;
        if      (i < 2097152) { s = s0; loc = i; }
        else if (i < 2883584) { s = s1; loc = i - 2097152; }
        else if (i < 3145728) { s = s2; loc = i - 2883584; }
        else if (i < 3342336) { s = s3; loc = i - 3145728; }
        else if (i < 3538944) { s = s4; loc = i - 3342336; }
        else                  { s = s5; loc = i - 3538944; }
        float4 v = *(const float4*)(s + (size_t)loc * 4);
        f16x4 o;
        o.x = (_Float16)v.x; o.y = (_Float16)v.y;
        o.z = (_Float16)v.z; o.w = (_Float16)v.w;
        *(f16x4*)(dst + (size_t)i * 4) = o;
    }
}

// ---------------------------------------------------------------------------
// MFMA GEMM: C[M,N] = A[M,K](fp16) @ W[N,K](fp16)^T + bias(fp32)
// BM=128, BK=64, BN template. 256 threads = 4 waves (2x2).
// XCD-chunked tile mapping: consecutive tiles within an XCD share A panels.
// blockIdx.y selects (W,bias,C) set (merged K/V projections).
// f16 output goes through an LDS re-tile for coalesced 16B stores.
// ---------------------------------------------------------------------------
template<int BN, int NN, typename OutT>
__global__ __launch_bounds__(256)
void gemm_h(const _Float16* __restrict__ A,
            const _Float16* __restrict__ W0, const float* __restrict__ bias0, OutT* __restrict__ C0,
            const _Float16* __restrict__ W1, const float* __restrict__ bias1, OutT* __restrict__ C1,
            int M, int N, int K)
{
    constexpr int BM = 128, BK = 64;
    constexpr int NF = BN / 32;               // n-frags per wave
    constexpr int SZ_T = BM * BK + BN * BK;   // staging halfwords
    constexpr int CL   = BN + 8;              // f16 epilogue stride (16B-aligned rows)
    constexpr int SZ_E = BM * CL;
    constexpr int LDSZ = SZ_T > SZ_E ? SZ_T : SZ_E;
    __shared__ alignas(16) _Float16 lds[LDSZ];
    _Float16* As = lds;
    _Float16* Ws = lds + BM * BK;

    const _Float16* W   = blockIdx.y ? W1 : W0;
    const float*   bias = blockIdx.y ? bias1 : bias0;
    OutT*          C    = blockIdx.y ? C1 : C0;

    const int tid = threadIdx.x;
    const int l   = tid & 63;
    const int w   = tid >> 6;
    const int wr  = w >> 1, wc = w & 1;

    // XCD-chunked tile decode (gridDim.x % 8 == 0 for all our launches)
    const int per  = gridDim.x >> 3;
    const int tile = (blockIdx.x & 7) * per + (blockIdx.x >> 3);
    const int m0   = (tile / NN) * BM;
    const int n0   = (tile % NN) * BN;

    // hoisted fragment LDS offsets (halfwords)
    int aOff[2][4], bOff[2][NF];
    #pragma unroll
    for (int kk = 0; kk < 2; ++kk) {
        #pragma unroll
        for (int m = 0; m < 4; ++m) {
            int rr = wr * 64 + m * 16 + (l & 15);
            aOff[kk][m] = rr * 64 + (((kk * 4 + (l >> 4)) ^ (rr & 7)) * 8);
        }
        #pragma unroll
        for (int n = 0; n < NF; ++n) {
            int rr = wc * (BN / 2) + n * 16 + (l & 15);
            bOff[kk][n] = rr * 64 + (((kk * 4 + (l >> 4)) ^ (rr & 7)) * 8);
        }
    }

    f32x4 acc[4][NF];
    #pragma unroll
    for (int m = 0; m < 4; ++m)
        #pragma unroll
        for (int n = 0; n < NF; ++n)
            acc[m][n] = (f32x4){0.f, 0.f, 0.f, 0.f};

    const int nk = K / BK;
    for (int kt = 0; kt < nk; ++kt) {
        const int k0 = kt * BK;
        #pragma unroll
        for (int it = 0; it < 4; ++it) {          // A: 128 rows x 8 slots
            int e = it * 256 + tid;
            int r = e >> 3, p = e & 7;
            async16(A + (size_t)(m0 + r) * K + k0 + ((p ^ (r & 7)) * 8),
                    &As[(size_t)(it * 256 + (tid & ~63)) * 8]);
        }
        #pragma unroll
        for (int it = 0; it < BN / 32; ++it) {    // W: BN rows x 8 slots
            int e = it * 256 + tid;
            int r = e >> 3, p = e & 7;
            async16(W + (size_t)(n0 + r) * K + k0 + ((p ^ (r & 7)) * 8),
                    &Ws[(size_t)(it * 256 + (tid & ~63)) * 8]);
        }
        __syncthreads();   // drains vmcnt -> tiles visible

        #pragma unroll
        for (int kk = 0; kk < 2; ++kk) {
            f16x8 af[4], bf[NF];
            #pragma unroll
            for (int m = 0; m < 4; ++m) af[m] = *(const f16x8*)&As[aOff[kk][m]];
            #pragma unroll
            for (int n = 0; n < NF; ++n) bf[n] = *(const f16x8*)&Ws[bOff[kk][n]];
            #pragma unroll
            for (int m = 0; m < 4; ++m)
                #pragma unroll
                for (int n = 0; n < NF; ++n)
                    acc[m][n] = __builtin_amdgcn_mfma_f32_16x16x32_f16(
                        af[m], bf[n], acc[m][n], 0, 0, 0);
        }
        __syncthreads();   // compute done -> safe to restage
    }

    float bv[NF];
    #pragma unroll
    for (int n = 0; n < NF; ++n)
        bv[n] = bias[n0 + wc * (BN / 2) + n * 16 + (l & 15)];

    if constexpr (sizeof(OutT) == 2) {
        // stash C tile in LDS (f16), then coalesced 16B stores
        _Float16* Ce = lds;
        #pragma unroll
        for (int m = 0; m < 4; ++m)
            #pragma unroll
            for (int n = 0; n < NF; ++n)
                #pragma unroll
                for (int r = 0; r < 4; ++r) {
                    int row = wr * 64 + m * 16 + (l >> 4) * 4 + r;
                    int col = wc * (BN / 2) + n * 16 + (l & 15);
                    Ce[row * CL + col] = (_Float16)(acc[m][n][r] + bv[n]);
                }
        __syncthreads();
        constexpr int SPR = BN / 8;   // f16x8 slots per row
        for (int i = tid; i < BM * SPR; i += 256) {
            int r = i / SPR, s = i % SPR;
            *(f16x8*)((_Float16*)C + (size_t)(m0 + r) * N + n0 + s * 8) =
                *(const f16x8*)&Ce[r * CL + s * 8];
        }
    } else {
        #pragma unroll
        for (int m = 0; m < 4; ++m)
            #pragma unroll
            for (int n = 0; n < NF; ++n)
                #pragma unroll
                for (int r = 0; r < 4; ++r) {
                    int row = m0 + wr * 64 + m * 16 + (l >> 4) * 4 + r;
                    int col = n0 + wc * (BN / 2) + n * 16 + (l & 15);
                    C[(size_t)row * N + col] = (OutT)(acc[m][n][r] + bv[n]);
                }
    }
}

// ---------------------------------------------------------------------------
// V transpose: Vh[b*NKV+kv][h*64+d] -> Vt[((b*16+h)*64+d)*512 + kv]
// ---------------------------------------------------------------------------
__global__ __launch_bounds__(256)
void transpose_v(const _Float16* __restrict__ Vh, _Float16* __restrict__ Vt)
{
    __shared__ alignas(16) _Float16 Ts[64 * 72];   // [kv][d], stride 72 hw
    const int tid = threadIdx.x;
    const int kvt = blockIdx.x, h = blockIdx.y, b = blockIdx.z;
    const int kv0 = kvt * 64;
    #pragma unroll
    for (int it = 0; it < 2; ++it) {
        int g = it * 256 + tid;
        int kv = g >> 3, d0 = (g & 7) * 8;
        *(f16x8*)&Ts[kv * 72 + d0] =
            *(const f16x8*)(Vh + (size_t)(b * NKV + kv0 + kv) * IN_DIM + h * 64 + d0);
    }
    __syncthreads();
    #pragma unroll
    for (int it = 0; it < 2; ++it) {
        int g = it * 256 + tid;
        int d = g >> 3, k0 = (g & 7) * 8;
        f16x8 v;
        #pragma unroll
        for (int j = 0; j < 8; ++j) v[j] = Ts[(k0 + j) * 72 + d];
        *(f16x8*)(Vt + ((size_t)((b * 16 + h) * 64 + d)) * NKV + kv0 + k0) = v;
    }
}

// ---------------------------------------------------------------------------
// MFMA flash attention v2. Block = 64 q-rows of one (b,h); 4 waves x 16 rows.
// 2-phase double-buffered K/V staging (one barrier per tile), exp2-domain
// online softmax with defer-rescale, setprio around MFMA, hoisted offsets,
// XCD-chunked block decode (all q-tiles of a (b,h) on one XCD).
// ---------------------------------------------------------------------------
__global__ __launch_bounds__(256)
void attn_mfma(const _Float16* __restrict__ Qh, const _Float16* __restrict__ Kh,
               const _Float16* __restrict__ Vt, _Float16* __restrict__ Ah)
{
    __shared__ alignas(16) _Float16 Ks[2][64 * 64];
    __shared__ alignas(16) _Float16 Vs[2][64 * 64];
    __shared__ alignas(16) _Float16 Pl[4][16 * 88];

    const int tid = threadIdx.x;
    const int l = tid & 63, w = tid >> 6;
    // XCD-chunked decode of 2048 blocks: xcd gets a contiguous (b,h) range
    const int t  = (blockIdx.x & 7) * 256 + (blockIdx.x >> 3);
    const int qt = t & 15, h = (t >> 4) & 15, b = t >> 8;
    const int q0 = qt * 64;

    // hoisted fragment offsets (halfwords) — same formula for Ks and Vs
    int frOff[2][4];
    #pragma unroll
    for (int kk = 0; kk < 2; ++kk)
        #pragma unroll
        for (int n = 0; n < 4; ++n) {
            int rr = n * 16 + (l & 15);
            frOff[kk][n] = rr * 64 + (((kk * 4 + (l >> 4)) ^ (rr & 7)) * 8);
        }
    const int pWr  = ((l >> 4) * 4) * 88 + (l & 15);   // + r*88 + n*16
    const int pRd0 = (l & 15) * 88 + (l >> 4) * 8;     // + kk*32

    const _Float16* Kbase = Kh + (size_t)(b * NKV) * IN_DIM + h * 64;
    const _Float16* Vbase = Vt + ((size_t)((b * 16 + h) * 64)) * NKV;

#define STAGE(buf, kv0) do {                                                   \
        _Pragma("unroll")                                                      \
        for (int it = 0; it < 2; ++it) {                                       \
            int e = it * 256 + tid; int r = e >> 3, p = e & 7;                 \
            async16(Kbase + (size_t)((kv0) + r) * IN_DIM + ((p ^ (r & 7)) * 8),\
                    &Ks[buf][(it * 256 + (tid & ~63)) * 8]);                   \
        }                                                                      \
        _Pragma("unroll")                                                      \
        for (int it = 0; it < 2; ++it) {                                       \
            int e = it * 256 + tid; int r = e >> 3, p = e & 7;                 \
            async16(Vbase + (size_t)r * NKV + (kv0) + ((p ^ (r & 7)) * 8),     \
                    &Vs[buf][(it * 256 + (tid & ~63)) * 8]);                   \
        }                                                                      \
    } while (0)

    // Q A-frags: lane l -> q-row w*16 + (l&15), k = kk*32 + (l>>4)*8 + j
    f16x8 qa[2];
    {
        const _Float16* qp = Qh + (size_t)(b * NQ + q0 + w * 16 + (l & 15)) * IN_DIM
                                + h * 64 + (l >> 4) * 8;
        qa[0] = *(const f16x8*)qp;
        qa[1] = *(const f16x8*)(qp + 32);
    }

    float m2[4], lr[4];
    f32x4 of[4];
    #pragma unroll
    for (int r = 0; r < 4; ++r) { m2[r] = -1e30f; lr[r] = 0.f; }
    #pragma unroll
    for (int d = 0; d < 4; ++d) of[d] = (f32x4){0.f, 0.f, 0.f, 0.f};

    STAGE(0, 0);
    __syncthreads();

    const float C2 = SCALE * 1.44269504f;   // fold log2(e): exp2 domain

    for (int kt = 0; kt < NKV / 64; ++kt) {
        const int cur = kt & 1;
        if (kt < NKV / 64 - 1) STAGE(cur ^ 1, (kt + 1) * 64);

        // ---- S = Q K^T ----
        __builtin_amdgcn_s_setprio(1);
        f32x4 sf[4];
        #pragma unroll
        for (int n = 0; n < 4; ++n) sf[n] = (f32x4){0.f, 0.f, 0.f, 0.f};
        #pragma unroll
        for (int kk = 0; kk < 2; ++kk)
            #pragma unroll
            for (int n = 0; n < 4; ++n)
                sf[n] = __builtin_amdgcn_mfma_f32_16x16x32_f16(
                    qa[kk], *(const f16x8*)&Ks[cur][frOff[kk][n]], sf[n], 0, 0, 0);
        __builtin_amdgcn_s_setprio(0);

        // ---- online softmax, exp2 domain; rows q=(l>>4)*4+r across 16 lanes
        float t4[4][4], pmax[4];
        bool need = false;
        #pragma unroll
        for (int r = 0; r < 4; ++r) {
            float a0 = sf[0][r] * C2, a1 = sf[1][r] * C2;
            float a2 = sf[2][r] * C2, a3 = sf[3][r] * C2;
            t4[r][0] = a0; t4[r][1] = a1; t4[r][2] = a2; t4[r][3] = a3;
            float mx = fmaxf(fmaxf(a0, a1), fmaxf(a2, a3));
            #pragma unroll
            for (int off = 1; off < 16; off <<= 1)
                mx = fmaxf(mx, __shfl_xor(mx, off));
            pmax[r] = mx;
            need |= (mx > m2[r] + 8.f);
        }
        if (__any((int)need)) {            // defer-rescale (T13)
            #pragma unroll
            for (int r = 0; r < 4; ++r) {
                float mn = fmaxf(m2[r], pmax[r]);
                float corr = fexp2(m2[r] - mn);
                m2[r] = mn;
                lr[r] *= corr;
                #pragma unroll
                for (int d = 0; d < 4; ++d) of[d][r] *= corr;
            }
        }
        #pragma unroll
        for (int r = 0; r < 4; ++r) {
            float p0 = fexp2(t4[r][0] - m2[r]);
            float p1 = fexp2(t4[r][1] - m2[r]);
            float p2 = fexp2(t4[r][2] - m2[r]);
            float p3 = fexp2(t4[r][3] - m2[r]);
            float rs = (p0 + p1) + (p2 + p3);
            #pragma unroll
            for (int off = 1; off < 16; off <<= 1)
                rs += __shfl_xor(rs, off);
            lr[r] += rs;
            Pl[w][pWr + r * 88 +  0] = (_Float16)p0;
            Pl[w][pWr + r * 88 + 16] = (_Float16)p1;
            Pl[w][pWr + r * 88 + 32] = (_Float16)p2;
            Pl[w][pWr + r * 88 + 48] = (_Float16)p3;
        }

        // ---- PV ----
        __builtin_amdgcn_s_setprio(1);
        #pragma unroll
        for (int kk = 0; kk < 2; ++kk) {
            f16x8 pa = *(const f16x8*)&Pl[w][pRd0 + kk * 32];
            #pragma unroll
            for (int d = 0; d < 4; ++d)
                of[d] = __builtin_amdgcn_mfma_f32_16x16x32_f16(
                    pa, *(const f16x8*)&Vs[cur][frOff[kk][d]], of[d], 0, 0, 0);
        }
        __builtin_amdgcn_s_setprio(0);
        __syncthreads();   // next tile staged (vmcnt drained) + buffers free
    }
#undef STAGE

    // ---- finalize ----
    #pragma unroll
    for (int r = 0; r < 4; ++r) lr[r] = 1.f / lr[r];
    #pragma unroll
    for (int d = 0; d < 4; ++d)
        #pragma unroll
        for (int r = 0; r < 4; ++r) {
            size_t row = (size_t)(b * NQ + q0 + w * 16 + (l >> 4) * 4 + r);
            Ah[row * IN_DIM + h * 64 + d * 16 + (l & 15)] = (_Float16)(of[d][r] * lr[r]);
        }
}

// ---------------------------------------------------------------------------
extern "C" void kernel_launch(void* const* d_in, const int* in_sizes, int n_in,
                              void* d_out, int out_size, void* d_ws, size_t ws_size,
                              hipStream_t stream)
{
    const float* x   = (const float*)d_in[0];
    const float* ctx = (const float*)d_in[1];
    const float* Wq  = (const float*)d_in[2];
    const float* bq  = (const float*)d_in[3];
    const float* Wk  = (const float*)d_in[4];
    const float* bk  = (const float*)d_in[5];
    const float* Wv  = (const float*)d_in[6];
    const float* bv  = (const float*)d_in[7];
    const float* Wo  = (const float*)d_in[8];
    const float* bo  = (const float*)d_in[9];
    float* out = (float*)d_out;

    // fp16 workspace layout (halfword offsets)
    _Float16* H = (_Float16*)d_ws;
    _Float16* xh   = H +        0;  // 8388608
    _Float16* ctxh = H +  8388608;  // 3145728
    _Float16* wqh  = H + 11534336;  // 1048576
    _Float16* wkh  = H + 12582912;  //  786432
    _Float16* wvh  = H + 13369344;  //  786432
    _Float16* woh  = H + 14155776;  // 1048576
    _Float16* Qh   = H + 15204352;  // 8388608
    _Float16* Kh   = H + 23592960;  // 4194304
    _Float16* Vh   = H + 27787264;  // 4194304
    _Float16* Vth  = H + 31981568;  // 4194304
    _Float16* Ah   = H + 36175872;  // 8388608

    const int MQ = BATCH * NQ;    // 8192
    const int MK = BATCH * NKV;   // 4096

    // 1) convert all fp32 inputs to fp16
    cvt6<<<2048, 256, 0, stream>>>(x, ctx, Wq, Wk, Wv, Wo, xh);

    // 2) projections: Q; K and V merged (blockIdx.y selects set)
    gemm_h<128, 8, _Float16><<<dim3(512, 1), 256, 0, stream>>>(
        xh, wqh, bq, Qh, wqh, bq, Qh, MQ, IN_DIM, IN_DIM);
    gemm_h<64, 16, _Float16><<<dim3(512, 2), 256, 0, stream>>>(
        ctxh, wkh, bk, Kh, wvh, bv, Vh, MK, IN_DIM, CTX_DIM);

    // 3) V -> [b,h,d,kv]
    transpose_v<<<dim3(NKV/64, NUM_HEADS, BATCH), 256, 0, stream>>>(Vh, Vth);

    // 4) attention
    attn_mfma<<<2048, 256, 0, stream>>>(Qh, Kh, Vth, Ah);

    // 5) output projection (fp32 out)
    gemm_h<128, 8, float><<<dim3(512, 1), 256, 0, stream>>>(
        Ah, woh, bo, out, woh, bo, out, MQ, IN_DIM, IN_DIM);
}

// Round 4
// 208.433 us; speedup vs baseline: 4.8733x; 1.2123x over previous
//
#include <hip/hip_runtime.h>
#include <math.h>

#define IN_DIM    1024
#define CTX_DIM   768
#define NUM_HEADS 16
#define HEAD_DIM  64
#define BATCH     8
#define NQ        1024
#define NKV       512
#define C2LOG     0.18033688f   // (1/sqrt(64)) * log2(e)

typedef __attribute__((ext_vector_type(8)))  _Float16 f16x8;
typedef __attribute__((ext_vector_type(4)))  _Float16 f16x4;
typedef __attribute__((ext_vector_type(2)))  _Float16 f16x2;
typedef __attribute__((ext_vector_type(4)))  float    f32x4;
typedef __attribute__((ext_vector_type(16))) float    f32x16;

// async global->LDS, 16B per lane. lds dest is wave-uniform base (+lane*16).
__device__ __forceinline__ void async16(const void* g, void* l) {
    __builtin_amdgcn_global_load_lds(
        (const __attribute__((address_space(1))) void*)g,
        (__attribute__((address_space(3))) void*)l, 16, 0, 0);
}

__device__ __forceinline__ float fexp2(float x) {
    float r; asm("v_exp_f32 %0, %1" : "=v"(r) : "v"(x)); return r;
}

// v_permlane32_swap_b32: a[32:63] <-> b[0:31]
__device__ __forceinline__ void plswap(int& a, int& b) {
    asm volatile("v_permlane32_swap_b32 %0, %1" : "+v"(a), "+v"(b));
}

// ---------------------------------------------------------------------------
// fp32 -> fp16 conversion of x, context, Wq, Wk, Wv, Wo (one contiguous dst).
// ---------------------------------------------------------------------------
__global__ __launch_bounds__(256)
void cvt6(const float* __restrict__ s0, const float* __restrict__ s1,
          const float* __restrict__ s2, const float* __restrict__ s3,
          const float* __restrict__ s4, const float* __restrict__ s5,
          _Float16* __restrict__ dst)
{
    const int stride = gridDim.x * blockDim.x;
    for (int i = blockIdx.x * blockDim.x + threadIdx.x; i < 3801088; i += stride) {
        const float* s; int loc;
        if      (i < 2097152) { s = s0; loc = i; }
        else if (i < 2883584) { s = s1; loc = i - 2097152; }
        else if (i < 3145728) { s = s2; loc = i - 2883584; }
        else if (i < 3342336) { s = s3; loc = i - 3145728; }
        else if (i < 3538944) { s = s4; loc = i - 3342336; }
        else                  { s = s5; loc = i - 3538944; }
        float4 v = *(const float4*)(s + (size_t)loc * 4);
        f16x4 o;
        o.x = (_Float16)v.x; o.y = (_Float16)v.y;
        o.z = (_Float16)v.z; o.w = (_Float16)v.w;
        *(f16x4*)(dst + (size_t)i * 4) = o;
    }
}

// ---------------------------------------------------------------------------
// MFMA GEMM: C[M,N] = A[M,K](f16) @ W[N,K](f16)^T + bias(f32)
// BM=128, BK=64, double-buffered LDS (2-phase: STAGE(t+1) before compute(t)).
// blockIdx.y selects (W,bias,C). TRV: y==1 epilogue writes V^T [b,h,d,kv].
// ---------------------------------------------------------------------------
template<int BN, int NN, bool TRV, typename OutT>
__global__ __launch_bounds__(256)
void gemm_h(const _Float16* __restrict__ A,
            const _Float16* __restrict__ W0, const float* __restrict__ bias0, OutT* __restrict__ C0,
            const _Float16* __restrict__ W1, const float* __restrict__ bias1, OutT* __restrict__ C1,
            int M, int N, int K)
{
    constexpr int BM = 128, BK = 64;
    constexpr int NF = BN / 32;
    constexpr int CL = BN + 8;
    __shared__ alignas(16) union {
        struct { _Float16 A[2][BM * BK]; _Float16 W[2][BN * BK]; } st;
        _Float16 ce[BM * CL];
    } lds;

    const _Float16* W   = blockIdx.y ? W1 : W0;
    const float*   bias = blockIdx.y ? bias1 : bias0;
    OutT*          C    = blockIdx.y ? C1 : C0;

    const int tid = threadIdx.x;
    const int l   = tid & 63;
    const int w   = tid >> 6;
    const int wr  = w >> 1, wc = w & 1;

    const int per  = gridDim.x >> 3;
    const int tile = (blockIdx.x & 7) * per + (blockIdx.x >> 3);
    const int m0   = (tile / NN) * BM;
    const int n0   = (tile % NN) * BN;

    int aOff[2][4], bOff[2][NF];
    #pragma unroll
    for (int kk = 0; kk < 2; ++kk) {
        #pragma unroll
        for (int m = 0; m < 4; ++m) {
            int rr = wr * 64 + m * 16 + (l & 15);
            aOff[kk][m] = rr * 64 + (((kk * 4 + (l >> 4)) ^ (rr & 7)) * 8);
        }
        #pragma unroll
        for (int n = 0; n < NF; ++n) {
            int rr = wc * (BN / 2) + n * 16 + (l & 15);
            bOff[kk][n] = rr * 64 + (((kk * 4 + (l >> 4)) ^ (rr & 7)) * 8);
        }
    }

    f32x4 acc[4][NF];
    #pragma unroll
    for (int m = 0; m < 4; ++m)
        #pragma unroll
        for (int n = 0; n < NF; ++n)
            acc[m][n] = (f32x4){0.f, 0.f, 0.f, 0.f};

#define GSTAGE(buf, k0) do {                                                    \
        _Pragma("unroll")                                                       \
        for (int it_ = 0; it_ < 4; ++it_) {                                     \
            int e = it_ * 256 + tid, r = e >> 3, p = e & 7;                     \
            async16(A + (size_t)(m0 + r) * K + (k0) + ((p ^ (r & 7)) * 8),      \
                    &lds.st.A[buf][(it_ * 256 + (tid & ~63)) * 8]);             \
        }                                                                       \
        _Pragma("unroll")                                                       \
        for (int it_ = 0; it_ < BN / 32; ++it_) {                               \
            int e = it_ * 256 + tid, r = e >> 3, p = e & 7;                     \
            async16(W + (size_t)(n0 + r) * K + (k0) + ((p ^ (r & 7)) * 8),      \
                    &lds.st.W[buf][(it_ * 256 + (tid & ~63)) * 8]);             \
        }                                                                       \
    } while (0)

    const int nk = K / BK;
    GSTAGE(0, 0);
    __syncthreads();

    for (int kt = 0; kt < nk; ++kt) {
        const int cur = kt & 1;
        if (kt + 1 < nk) GSTAGE(cur ^ 1, (kt + 1) * BK);

        const _Float16* As = lds.st.A[cur];
        const _Float16* Ws = lds.st.W[cur];
        #pragma unroll
        for (int kk = 0; kk < 2; ++kk) {
            f16x8 af[4], bf[NF];
            #pragma unroll
            for (int m = 0; m < 4; ++m) af[m] = *(const f16x8*)&As[aOff[kk][m]];
            #pragma unroll
            for (int n = 0; n < NF; ++n) bf[n] = *(const f16x8*)&Ws[bOff[kk][n]];
            #pragma unroll
            for (int m = 0; m < 4; ++m)
                #pragma unroll
                for (int n = 0; n < NF; ++n)
                    acc[m][n] = __builtin_amdgcn_mfma_f32_16x16x32_f16(
                        af[m], bf[n], acc[m][n], 0, 0, 0);
        }
        __syncthreads();   // drains next-tile vmcnt + protects buffer reuse
    }
#undef GSTAGE

    float bv[NF];
    #pragma unroll
    for (int n = 0; n < NF; ++n)
        bv[n] = bias[n0 + wc * (BN / 2) + n * 16 + (l & 15)];

    if constexpr (sizeof(OutT) == 2) {
        #pragma unroll
        for (int m = 0; m < 4; ++m)
            #pragma unroll
            for (int n = 0; n < NF; ++n)
                #pragma unroll
                for (int r = 0; r < 4; ++r) {
                    int row = wr * 64 + m * 16 + (l >> 4) * 4 + r;
                    int col = wc * (BN / 2) + n * 16 + (l & 15);
                    lds.ce[row * CL + col] = (_Float16)(acc[m][n][r] + bv[n]);
                }
        __syncthreads();
        bool trv = TRV && (blockIdx.y == 1);
        if (TRV && trv) {
            // V^T epilogue: Vt[((b*16+h)*64 + d)*NKV + kv]
            const int bb = m0 >> 9, kv0 = m0 & 511, hh = n0 >> 6;
            for (int i = tid; i < 64 * 16; i += 256) {
                int d = i & 63, c = i >> 6;
                f16x8 v;
                #pragma unroll
                for (int j = 0; j < 8; ++j) v[j] = lds.ce[(c * 8 + j) * CL + d];
                *(f16x8*)((_Float16*)C + ((size_t)(bb * 16 + hh) * 64 + d) * NKV
                                       + kv0 + c * 8) = v;
            }
        } else {
            constexpr int SPR = BN / 8;
            for (int i = tid; i < BM * SPR; i += 256) {
                int r = i / SPR, s = i % SPR;
                *(f16x8*)((_Float16*)C + (size_t)(m0 + r) * N + n0 + s * 8) =
                    *(const f16x8*)&lds.ce[r * CL + s * 8];
            }
        }
    } else {
        #pragma unroll
        for (int m = 0; m < 4; ++m)
            #pragma unroll
            for (int n = 0; n < NF; ++n)
                #pragma unroll
                for (int r = 0; r < 4; ++r) {
                    int row = m0 + wr * 64 + m * 16 + (l >> 4) * 4 + r;
                    int col = n0 + wc * (BN / 2) + n * 16 + (l & 15);
                    C[(size_t)row * N + col] = (OutT)(acc[m][n][r] + bv[n]);
                }
    }
}

// ---------------------------------------------------------------------------
// MFMA flash attention v3 — swapped-QK 32x32 structure (T12).
// Block = 128 q-rows of one (b,h); 4 waves x 32 q. KVBLK=64 double-buffered.
// S^T = mfma(K, Q): lane owns q-col (l&31), kv rows in regs -> softmax is an
// in-register tree + one shfl_xor(32). P packed f16 + permlane32_swap feeds
// PV = mfma(V^T, P^T) directly. Output re-tiled via LDS for 16B stores.
// ---------------------------------------------------------------------------
__global__ __launch_bounds__(256)
void attn_mfma(const _Float16* __restrict__ Qh, const _Float16* __restrict__ Kh,
               const _Float16* __restrict__ Vt, _Float16* __restrict__ Ah)
{
    __shared__ alignas(16) union {
        struct { _Float16 K[2][64 * 64]; _Float16 V[2][64 * 64]; } st;   // 32 KB
        _Float16 ot[4][32 * 72];                                         // 18 KB
    } lds;

    const int tid = threadIdx.x;
    const int l = tid & 63, w = tid >> 6;
    const int hi = l >> 5, ln = l & 31;
    // XCD-chunked decode: 1024 blocks, each XCD = one batch
    const int t  = ((int)blockIdx.x & 7) * 128 + ((int)blockIdx.x >> 3);
    const int qt = t & 7, h = (t >> 3) & 15, b = t >> 7;
    const int q0 = qt * 128;

    // Q as B-operand frags (pre-scaled into exp2 domain):
    // lane: q = q0 + w*32 + ln, k(d) = ks*16 + hi*8 + j
    f16x8 qa[4];
    {
        const _Float16* qp = Qh + ((size_t)(b * NQ) + q0 + w * 32 + ln) * IN_DIM
                                + h * 64 + hi * 8;
        #pragma unroll
        for (int ks = 0; ks < 4; ++ks) qa[ks] = *(const f16x8*)(qp + ks * 16);
        #pragma unroll
        for (int ks = 0; ks < 4; ++ks)
            #pragma unroll
            for (int j = 0; j < 8; ++j) qa[ks][j] *= (_Float16)C2LOG;
    }

    const _Float16* Kbase = Kh + (size_t)(b * NKV) * IN_DIM + h * 64;
    const _Float16* Vbase = Vt + ((size_t)(b * 16 + h) * 64) * NKV;

#define STAGE(buf, kv0) do {                                                     \
        _Pragma("unroll")                                                        \
        for (int it_ = 0; it_ < 2; ++it_) {                                      \
            int e = it_ * 256 + tid, r = e >> 3, p = e & 7;                      \
            async16(Kbase + (size_t)((kv0) + r) * IN_DIM + ((p ^ (r & 7)) * 8),  \
                    &lds.st.K[buf][(it_ * 256 + (tid & ~63)) * 8]);              \
        }                                                                        \
        _Pragma("unroll")                                                        \
        for (int it_ = 0; it_ < 2; ++it_) {                                      \
            int e = it_ * 256 + tid, r = e >> 3, p = e & 7;                      \
            async16(Vbase + (size_t)r * NKV + (kv0) + ((p ^ (r & 7)) * 8),       \
                    &lds.st.V[buf][(it_ * 256 + (tid & ~63)) * 8]);              \
        }                                                                        \
    } while (0)

    f32x16 oacc[2];
    #pragma unroll
    for (int dt = 0; dt < 2; ++dt)
        #pragma unroll
        for (int i = 0; i < 16; ++i) oacc[dt][i] = 0.f;
    float m2 = -1e30f, lr = 0.f;

    STAGE(0, 0);
    __syncthreads();

    for (int kt = 0; kt < NKV / 64; ++kt) {
        const int cur = kt & 1;
        if (kt < NKV / 64 - 1) STAGE(cur ^ 1, (kt + 1) * 64);

        // ---- S^T = K·Q^T (exp2 domain already) ----
        f32x16 sf[2];
        #pragma unroll
        for (int st = 0; st < 2; ++st)
            #pragma unroll
            for (int i = 0; i < 16; ++i) sf[st][i] = 0.f;

        __builtin_amdgcn_s_setprio(1);
        #pragma unroll
        for (int st = 0; st < 2; ++st) {
            int kvr = st * 32 + ln;
            #pragma unroll
            for (int ks = 0; ks < 4; ++ks) {
                f16x8 kf = *(const f16x8*)
                    &lds.st.K[cur][kvr * 64 + (((ks * 2 + hi) ^ (kvr & 7)) * 8)];
                sf[st] = __builtin_amdgcn_mfma_f32_32x32x16_f16(kf, qa[ks], sf[st], 0, 0, 0);
            }
        }
        __builtin_amdgcn_s_setprio(0);

        // ---- softmax over 64 kv: in-register tree + one cross-half swap ----
        float t0[16];
        #pragma unroll
        for (int i = 0; i < 16; ++i) t0[i] = fmaxf(sf[0][i], sf[1][i]);
        #pragma unroll
        for (int s = 8; s; s >>= 1)
            #pragma unroll
            for (int i = 0; i < s; ++i) t0[i] = fmaxf(t0[i], t0[i + s]);
        float pmax = fmaxf(t0[0], __shfl_xor(t0[0], 32));

        if (__any((int)(pmax > m2 + 8.f))) {   // defer-rescale (T13)
            float mn = fmaxf(m2, pmax);
            float corr = fexp2(m2 - mn);
            lr *= corr; m2 = mn;
            #pragma unroll
            for (int dt = 0; dt < 2; ++dt)
                #pragma unroll
                for (int i = 0; i < 16; ++i) oacc[dt][i] *= corr;
        }

        #pragma unroll
        for (int st = 0; st < 2; ++st)
            #pragma unroll
            for (int i = 0; i < 16; ++i) sf[st][i] = fexp2(sf[st][i] - m2);

        #pragma unroll
        for (int i = 0; i < 16; ++i) t0[i] = sf[0][i] + sf[1][i];
        #pragma unroll
        for (int s = 8; s; s >>= 1)
            #pragma unroll
            for (int i = 0; i < s; ++i) t0[i] += t0[i + s];
        lr += t0[0] + __shfl_xor(t0[0], 32);

        // ---- pack P to f16 pairs, permlane-swap into B-frag order ----
        int wds[2][8];
        #pragma unroll
        for (int st = 0; st < 2; ++st)
            #pragma unroll
            for (int i = 0; i < 8; ++i) {
                f16x2 p2; p2.x = (_Float16)sf[st][2 * i]; p2.y = (_Float16)sf[st][2 * i + 1];
                wds[st][i] = __builtin_bit_cast(int, p2);
            }
        #pragma unroll
        for (int st = 0; st < 2; ++st) {
            plswap(wds[st][0], wds[st][2]);
            plswap(wds[st][1], wds[st][3]);
            plswap(wds[st][4], wds[st][6]);
            plswap(wds[st][5], wds[st][7]);
        }

        // ---- O^T += V^T · P^T ----
        __builtin_amdgcn_s_setprio(1);
        #pragma unroll
        for (int st = 0; st < 2; ++st)
            #pragma unroll
            for (int ks2 = 0; ks2 < 2; ++ks2) {
                union { int i[4]; f16x8 v; } pu;
                #pragma unroll
                for (int k = 0; k < 4; ++k) pu.i[k] = wds[st][ks2 * 4 + k];
                #pragma unroll
                for (int dt = 0; dt < 2; ++dt) {
                    int dr = dt * 32 + ln;
                    f16x8 vf = *(const f16x8*)
                        &lds.st.V[cur][dr * 64 + (((st * 4 + ks2 * 2 + hi) ^ (dr & 7)) * 8)];
                    oacc[dt] = __builtin_amdgcn_mfma_f32_32x32x16_f16(vf, pu.v, oacc[dt], 0, 0, 0);
                }
            }
        __builtin_amdgcn_s_setprio(0);
        __syncthreads();   // next tile staged; buffers reusable
    }
#undef STAGE

    // ---- epilogue: normalize, re-tile via LDS, coalesced 16B stores ----
    __syncthreads();   // all waves done with staging LDS
    float inv = 1.f / lr;
    #pragma unroll
    for (int dt = 0; dt < 2; ++dt)
        #pragma unroll
        for (int rq = 0; rq < 4; ++rq) {
            f16x4 v;
            #pragma unroll
            for (int k = 0; k < 4; ++k)
                v[k] = (_Float16)(oacc[dt][rq * 4 + k] * inv);
            int d0 = dt * 32 + rq * 8 + hi * 4;
            *(f16x4*)&lds.ot[w][ln * 72 + d0] = v;
        }
    __syncthreads();
    #pragma unroll
    for (int it = 0; it < 4; ++it) {
        int i = it * 256 + tid;
        int q = i >> 3, s = i & 7;
        f16x8 v = *(const f16x8*)&lds.ot[q >> 5][(q & 31) * 72 + s * 8];
        *(f16x8*)(Ah + ((size_t)(b * NQ) + q0 + q) * IN_DIM + h * 64 + s * 8) = v;
    }
}

// ---------------------------------------------------------------------------
extern "C" void kernel_launch(void* const* d_in, const int* in_sizes, int n_in,
                              void* d_out, int out_size, void* d_ws, size_t ws_size,
                              hipStream_t stream)
{
    const float* x   = (const float*)d_in[0];
    const float* ctx = (const float*)d_in[1];
    const float* Wq  = (const float*)d_in[2];
    const float* bq  = (const float*)d_in[3];
    const float* Wk  = (const float*)d_in[4];
    const float* bk  = (const float*)d_in[5];
    const float* Wv  = (const float*)d_in[6];
    const float* bv  = (const float*)d_in[7];
    const float* Wo  = (const float*)d_in[8];
    const float* bo  = (const float*)d_in[9];
    float* out = (float*)d_out;

    // fp16 workspace layout (halfword offsets)
    _Float16* H = (_Float16*)d_ws;
    _Float16* xh   = H +        0;  // 8388608
    _Float16* ctxh = H +  8388608;  // 3145728
    _Float16* wqh  = H + 11534336;  // 1048576
    _Float16* wkh  = H + 12582912;  //  786432
    _Float16* wvh  = H + 13369344;  //  786432
    _Float16* woh  = H + 14155776;  // 1048576
    _Float16* Qh   = H + 15204352;  // 8388608
    _Float16* Kh   = H + 23592960;  // 4194304
    _Float16* Vth  = H + 31981568;  // 4194304
    _Float16* Ah   = H + 36175872;  // 8388608

    const int MQ = BATCH * NQ;    // 8192
    const int MK = BATCH * NKV;   // 4096

    // 1) convert all fp32 inputs to fp16
    cvt6<<<2048, 256, 0, stream>>>(x, ctx, Wq, Wk, Wv, Wo, xh);

    // 2) projections: Q; K and V merged (V epilogue writes V^T directly)
    gemm_h<128, 8, false, _Float16><<<dim3(512, 1), 256, 0, stream>>>(
        xh, wqh, bq, Qh, wqh, bq, Qh, MQ, IN_DIM, IN_DIM);
    gemm_h<64, 16, true, _Float16><<<dim3(512, 2), 256, 0, stream>>>(
        ctxh, wkh, bk, Kh, wvh, bv, Vth, MK, IN_DIM, CTX_DIM);

    // 3) attention (1024 blocks: 8 qt x 16 h x 8 b)
    attn_mfma<<<1024, 256, 0, stream>>>(Qh, Kh, Vth, Ah);

    // 4) output projection (fp32 out)
    gemm_h<128, 8, false, float><<<dim3(512, 1), 256, 0, stream>>>(
        Ah, woh, bo, out, woh, bo, out, MQ, IN_DIM, IN_DIM);
}